// Round 7
// baseline (36007.532 us; speedup 1.0000x reference)
//
#include <hip/hip_runtime.h>
#include <stdint.h>
#include <stddef.h>

#define BB 32
#define TT 64
#define DD 512
#define HH 8
#define HDIM 64
#define LL 4
#define FFD 2048
#define VV 128

#define NBLK 256
#define NTHR 512

// ---------------- threefry2x32 (20 rounds), matches JAX ----------------
__host__ __device__ inline uint32_t rotl32(uint32_t v, int n){ return (v << n) | (v >> (32 - n)); }

__host__ __device__ inline void tf2x32(uint32_t k0, uint32_t k1, uint32_t x0, uint32_t x1,
                                       uint32_t* o0, uint32_t* o1){
  uint32_t ks2 = k0 ^ k1 ^ 0x1BD11BDAu;
  x0 += k0; x1 += k1;
  x0 += x1; x1 = rotl32(x1,13); x1 ^= x0;
  x0 += x1; x1 = rotl32(x1,15); x1 ^= x0;
  x0 += x1; x1 = rotl32(x1,26); x1 ^= x0;
  x0 += x1; x1 = rotl32(x1, 6); x1 ^= x0;
  x0 += k1; x1 += ks2 + 1u;
  x0 += x1; x1 = rotl32(x1,17); x1 ^= x0;
  x0 += x1; x1 = rotl32(x1,29); x1 ^= x0;
  x0 += x1; x1 = rotl32(x1,16); x1 ^= x0;
  x0 += x1; x1 = rotl32(x1,24); x1 ^= x0;
  x0 += ks2; x1 += k0 + 2u;
  x0 += x1; x1 = rotl32(x1,13); x1 ^= x0;
  x0 += x1; x1 = rotl32(x1,15); x1 ^= x0;
  x0 += x1; x1 = rotl32(x1,26); x1 ^= x0;
  x0 += x1; x1 = rotl32(x1, 6); x1 ^= x0;
  x0 += k0; x1 += k1 + 3u;
  x0 += x1; x1 = rotl32(x1,17); x1 ^= x0;
  x0 += x1; x1 = rotl32(x1,29); x1 ^= x0;
  x0 += x1; x1 = rotl32(x1,16); x1 ^= x0;
  x0 += x1; x1 = rotl32(x1,24); x1 ^= x0;
  x0 += k1; x1 += ks2 + 4u;
  x0 += x1; x1 = rotl32(x1,13); x1 ^= x0;
  x0 += x1; x1 = rotl32(x1,15); x1 ^= x0;
  x0 += x1; x1 = rotl32(x1,26); x1 ^= x0;
  x0 += x1; x1 = rotl32(x1, 6); x1 ^= x0;
  x0 += ks2; x1 += k0 + 5u;
  *o0 = x0; *o1 = x1;
}

// ---------------- helpers ----------------
__device__ inline float dot_f4(const float* __restrict__ a, const float* __restrict__ w, int K){
  float acc = 0.f;
  const float4* a4 = (const float4*)a;
  const float4* w4 = (const float4*)w;
  int K4 = K >> 2;
  for (int k = 0; k < K4; ++k){
    float4 av = a4[k], wv = w4[k];
    acc = fmaf(av.x, wv.x, acc);
    acc = fmaf(av.y, wv.y, acc);
    acc = fmaf(av.z, wv.z, acc);
    acc = fmaf(av.w, wv.w, acc);
  }
  return acc;
}

// LayerNorm across a 512-thread block (one value per thread). Round-1 exact order.
__device__ inline float block_ln(float v, float g, float bb, float* red){
  __syncthreads();
  float s = v;
  #pragma unroll
  for (int off = 32; off; off >>= 1) s += __shfl_xor(s, off);
  if ((threadIdx.x & 63) == 0) red[threadIdx.x >> 6] = s;
  __syncthreads();
  float mu = (red[0]+red[1]+red[2]+red[3]+red[4]+red[5]+red[6]+red[7]) * (1.0f/512.0f);
  float dv = v - mu;
  float sq = dv * dv;
  #pragma unroll
  for (int off = 32; off; off >>= 1) sq += __shfl_xor(sq, off);
  __syncthreads();
  if ((threadIdx.x & 63) == 0) red[threadIdx.x >> 6] = sq;
  __syncthreads();
  float var = (red[0]+red[1]+red[2]+red[3]+red[4]+red[5]+red[6]+red[7]) * (1.0f/512.0f);
  return dv * (1.0f / sqrtf(var + 1e-5f)) * g + bb;
}

// ---------------- global barrier v3: 3-level arrival tree + distributed release flags ----
// bar layout (uints): sub[i]=bar[i*16] (i<32, 8 blocks each: sub = bid>>3)
//                     mid[j]=bar[512+j*16] (j<4, 8 subs each)
//                     root =bar[640] (4 arrivals)
//                     flag[i]=bar[1024+i*16] (release flag per sub; holds epoch)
__device__ __forceinline__ void gbarAll(unsigned* bar, unsigned epoch, int* done){
  const int tid = threadIdx.x;
  const int sub = blockIdx.x >> 3;
  __syncthreads();
  if (tid == 0){
    __builtin_amdgcn_fence(__ATOMIC_RELEASE, "agent");
    int c = 0;
    if (__hip_atomic_fetch_add(bar + sub*16, 1u, __ATOMIC_RELAXED, __HIP_MEMORY_SCOPE_AGENT) == 7u){
      int mid = sub >> 3;
      if (__hip_atomic_fetch_add(bar + 512 + mid*16, 1u, __ATOMIC_RELAXED, __HIP_MEMORY_SCOPE_AGENT) == 7u){
        if (__hip_atomic_fetch_add(bar + 640, 1u, __ATOMIC_RELAXED, __HIP_MEMORY_SCOPE_AGENT) == 3u)
          c = 1;
      }
    }
    *done = c;
  }
  __syncthreads();
  if (*done){
    // completer block: parallel counter reset, then parallel flag publish
    if (tid < 32)      __hip_atomic_store(bar + tid*16,            0u, __ATOMIC_RELAXED, __HIP_MEMORY_SCOPE_AGENT);
    else if (tid < 36) __hip_atomic_store(bar + 512 + (tid-32)*16, 0u, __ATOMIC_RELAXED, __HIP_MEMORY_SCOPE_AGENT);
    else if (tid == 36)__hip_atomic_store(bar + 640,               0u, __ATOMIC_RELAXED, __HIP_MEMORY_SCOPE_AGENT);
    __syncthreads();
    if (tid == 0) __builtin_amdgcn_fence(__ATOMIC_RELEASE, "agent");
    __syncthreads();
    if (tid < 32) __hip_atomic_store(bar + 1024 + tid*16, epoch, __ATOMIC_RELAXED, __HIP_MEMORY_SCOPE_AGENT);
  } else {
    if (tid == 0){
      while (__hip_atomic_load(bar + 1024 + sub*16, __ATOMIC_RELAXED, __HIP_MEMORY_SCOPE_AGENT) < epoch)
        __builtin_amdgcn_s_sleep(1);
    }
  }
  if (tid == 0) __builtin_amdgcn_fence(__ATOMIC_ACQUIRE, "agent");
  __syncthreads();
}

// ---------------- setup kernels ----------------
__global__ void k_tables(float* __restrict__ cosb, float* __restrict__ sinb){
  int tid = blockIdx.x * blockDim.x + threadIdx.x;  // TT*256
  int p = tid >> 8, i = tid & 255;
  float sv = (2.0f * (float)i + 204.8f) / 716.8f;
  float scale = powf(sv, (float)p / 16.0f);
  float invf = 1.0f / powf(10000.0f, (float)i / 256.0f);
  float ang = (float)p * invf;
  cosb[tid] = cosf(ang) * scale;
  sinb[tid] = sinf(ang) * scale;
}

__global__ void k_ca1(const float* __restrict__ mol, const float* __restrict__ w,
                      const float* __restrict__ bias, float* __restrict__ tmp){
  int tid = blockIdx.x * blockDim.x + threadIdx.x;  // LL*BB*DD
  int l = tid >> 14; int r = tid & 16383; int b = r >> 9; int d = r & 511;
  const float* wr = w + (size_t)l*3*DD*DD + (size_t)(2*DD + d)*DD;
  tmp[tid] = bias[l*3*DD + 2*DD + d] + dot_f4(mol + (size_t)b*DD, wr, DD);
}

__global__ void k_ca2(const float* __restrict__ tmp, const float* __restrict__ w,
                      const float* __restrict__ bias, float* __restrict__ cac){
  int tid = blockIdx.x * blockDim.x + threadIdx.x;  // LL*BB*DD
  int l = tid >> 14; int r = tid & 16383; int b = r >> 9; int d = r & 511;
  const float* wr = w + (size_t)l*DD*DD + (size_t)d*DD;
  cac[tid] = bias[l*DD + d] + dot_f4(tmp + ((size_t)l*BB + b)*DD, wr, DD);
}

__global__ void k_binit(unsigned* __restrict__ bar, int* __restrict__ pred){
  int tid = threadIdx.x;            // 1024 threads
  bar[tid] = 0u;
  bar[tid + 1024] = 0u;
  pred[tid]        = ((tid & (TT-1)) == 0) ? 1 : 0;
  pred[tid + 1024] = (((tid + 1024) & (TT-1)) == 0) ? 1 : 0;
}

// ---------------- generic matmul partials ----------------
// W [N][KTOT] row-major (original layout); act [32][ASTRIDE]; C cols per block.
// 8 k-chunk partials per output, w-ascending combine later: exact r4/r5/r6 sum shape.
template<int C, int KTOT, int ASTRIDE>
__device__ __forceinline__ void mm_part(const float* __restrict__ W,
                                        const float* __restrict__ act,
                                        int n0, float* __restrict__ part){
  const int tid = threadIdx.x;
  const int KC = KTOT/8;
  #pragma unroll
  for (int i = 0; i < (C*256)/512; ++i){
    int tau = tid + i*512;
    int r = tau & 31, rest = tau >> 5;
    int c = rest % C, w = rest / C;
    const float4* wr = (const float4*)(W + (size_t)(n0 + c)*KTOT + w*KC);
    const float4* ar = (const float4*)(act + (size_t)r*ASTRIDE + w*KC);
    float acc = 0.f;
    #pragma unroll 8
    for (int k4 = 0; k4 < KC/4; ++k4){
      float4 wv = wr[k4], av = ar[k4];
      acc = fmaf(av.x, wv.x, acc);
      acc = fmaf(av.y, wv.y, acc);
      acc = fmaf(av.z, wv.z, acc);
      acc = fmaf(av.w, wv.w, acc);
    }
    part[(w*C + c)*32 + r] = acc;
  }
  __syncthreads();
}

// ---------------- persistent decode kernel ----------------
struct KParams {
  const float *emb, *saw, *sab, *sow, *sob, *f1w, *f1b, *f2w, *f2b;
  const float *g1,*b1,*g2,*b2,*g3,*b3,*fg,*fb;
  const float *o1w,*o1b,*o2w,*o2b,*o3w,*o3b;
  const float *cosb,*sinb,*cac;
  float *kc,*vc,*xl,*qb,*at,*ao,*x2,*fo,*h1,*xf,*hh1,*hh2;
  int *pred;
  unsigned *bar;
};

__global__ __launch_bounds__(NTHR) void k_persist(KParams P){
  const int bid = blockIdx.x, tid = threadIdx.x;
  const int lane = tid & 63;
  __shared__ __align__(16) float smem[2176];
  float* part = smem;                  // 2048
  float* red  = smem + 2048;           // 8
  int*   redi = (int*)(smem + 2056);   // 2
  int*   stok = (int*)(smem + 2060);   // 1
  int*   done = (int*)(smem + 2064);   // 1 (barrier scratch)
  unsigned epoch = 0;

  // ---- pre-loop: embed position 0 (rows on blocks 0..31) ----
  if (bid < 32){
    int rb = bid, d = tid;
    int tok = P.pred[rb*TT + 0];
    int i = d >> 1;
    float c = P.cosb[0*256 + i], s = P.sinb[0*256 + i];
    float e0 = P.emb[(size_t)tok*DD + (d & ~1)];
    float e1 = P.emb[(size_t)tok*DD + (d | 1)];
    P.xl[rb*DD + d] = (d & 1) ? fmaf(e1, c, e0*s) : fmaf(e0, c, -(e1*s));
  }
  gbarAll(P.bar, ++epoch, done);

  for (int t = 1; t < TT; ++t){
    const int pp = t - 1;

    for (int l = 0; l < LL; ++l){
      // ---- S1: QKV, N=1536, 6 cols/block ----
      mm_part<6,512,512>(P.saw + (size_t)l*1536*512, P.xl, bid*6, part);
      if (tid < 192){
        int r = tid & 31, c = tid >> 5;
        int n = bid*6 + c;
        float s = P.sab[l*1536 + n];
        #pragma unroll
        for (int w = 0; w < 8; ++w) s += part[(w*6 + c)*32 + r];
        if (n < DD){
          P.qb[(size_t)r*DD + n] = s;
        } else if (n < 2*DD){
          int h = (n - DD) >> 6, hd = (n - DD) & 63;
          P.kc[((((size_t)l*BB + r)*HH + h)*TT + pp)*HDIM + hd] = s;
        } else {
          int h = (n - 2*DD) >> 6, hd = (n - 2*DD) & 63;
          P.vc[((((size_t)l*BB + r)*HH + h)*TT + pp)*HDIM + hd] = s;
        }
      }
      gbarAll(P.bar, ++epoch, done);

      // ---- S2: attention, block = (row, head), 1 wave ----
      {
        int rb = bid >> 3, h = bid & 7;
        float* qs = smem; float* ps = smem + 64;
        if (tid < 64) qs[tid] = P.qb[(size_t)rb*DD + h*HDIM + tid];
        __syncthreads();
        if (tid < 64){
          const float* kb = P.kc + (((size_t)l*BB + rb)*HH + h)*TT*HDIM;
          float s = -INFINITY;
          if (lane <= pp && P.pred[rb*TT + lane] != 0){
            const float* kr = kb + lane*HDIM;
            float acc = 0.f;
            #pragma unroll
            for (int k2 = 0; k2 < HDIM; ++k2) acc = fmaf(qs[k2], kr[k2], acc);
            s = acc * 0.125f;
          }
          float mx = s;
          #pragma unroll
          for (int off = 32; off; off >>= 1) mx = fmaxf(mx, __shfl_xor(mx, off));
          float e = (s == -INFINITY) ? 0.f : expf(s - mx);
          float sum = e;
          #pragma unroll
          for (int off = 32; off; off >>= 1) sum += __shfl_xor(sum, off);
          ps[lane] = e / sum;
          const float* vb = P.vc + (((size_t)l*BB + rb)*HH + h)*TT*HDIM;
          float o = 0.f;
          int jj = 0;
          for (; jj + 8 <= t; jj += 8){
            float vv[8];
            #pragma unroll
            for (int u = 0; u < 8; ++u) vv[u] = vb[(jj+u)*HDIM + lane];
            #pragma unroll
            for (int u = 0; u < 8; ++u) o = fmaf(ps[jj+u], vv[u], o);
          }
          for (; jj <= pp; ++jj) o = fmaf(ps[jj], vb[jj*HDIM + lane], o);
          P.at[(size_t)rb*DD + h*HDIM + lane] = o;
        }
      }
      gbarAll(P.bar, ++epoch, done);

      // ---- S3: oproj, N=512, 2 cols/block ----
      mm_part<2,512,512>(P.sow + (size_t)l*512*512, P.at, bid*2, part);
      if (tid < 64){
        int r = tid & 31, c = tid >> 5;
        int n = bid*2 + c;
        float s = P.sob[l*DD + n];
        #pragma unroll
        for (int w = 0; w < 8; ++w) s += part[(w*2 + c)*32 + r];
        P.ao[(size_t)r*DD + n] = s;
      }
      gbarAll(P.bar, ++epoch, done);

      // ---- S4: residual + ln1 + cross const + ln2 (32 row blocks) ----
      if (bid < 32){
        int b = bid, d = tid;
        float xv = P.xl[(size_t)b*DD + d] + P.ao[(size_t)b*DD + d];
        xv = block_ln(xv, P.g1[l*DD + d], P.b1[l*DD + d], red);
        xv = xv + P.cac[((size_t)l*BB + b)*DD + d];
        xv = block_ln(xv, P.g2[l*DD + d], P.b2[l*DD + d], red);
        P.x2[(size_t)b*DD + d] = xv;
      }
      gbarAll(P.bar, ++epoch, done);

      // ---- S5: FF1, N=2048, 8 cols/block, silu ----
      mm_part<8,512,512>(P.f1w + (size_t)l*2048*512, P.x2, bid*8, part);
      if (tid < 256){
        int r = tid & 31, c = tid >> 5;
        int n = bid*8 + c;
        float v = P.f1b[l*FFD + n];
        #pragma unroll
        for (int w = 0; w < 8; ++w) v += part[(w*8 + c)*32 + r];
        P.h1[(size_t)r*FFD + n] = v / (1.0f + expf(-v));
      }
      gbarAll(P.bar, ++epoch, done);

      // ---- S6: FF2, N=512, K=2048, 2 cols/block ----
      mm_part<2,2048,2048>(P.f2w + (size_t)l*512*2048, P.h1, bid*2, part);
      if (tid < 64){
        int r = tid & 31, c = tid >> 5;
        int n = bid*2 + c;
        float s = P.f2b[l*DD + n];
        #pragma unroll
        for (int w = 0; w < 8; ++w) s += part[(w*2 + c)*32 + r];
        P.fo[(size_t)r*DD + n] = s;
      }
      gbarAll(P.bar, ++epoch, done);

      // ---- S7: residual + ln3 (+ final ln at last layer) (32 row blocks) ----
      if (bid < 32){
        int b = bid, d = tid;
        float y = P.x2[(size_t)b*DD + d] + P.fo[(size_t)b*DD + d];
        float xv = block_ln(y, P.g3[l*DD + d], P.b3[l*DD + d], red);
        if (l < LL-1){
          P.xl[(size_t)b*DD + d] = xv;
        } else {
          float o = block_ln(xv, P.fg[d], P.fb[d], red);
          P.xf[(size_t)b*DD + d] = o;
        }
      }
      gbarAll(P.bar, ++epoch, done);
    }

    // ---- S8: head1, N=1024, 4 cols/block, gelu ----
    mm_part<4,512,512>(P.o1w, P.xf, bid*4, part);
    if (tid < 128){
      int r = tid & 31, c = tid >> 5;
      int n = bid*4 + c;
      float a = P.o1b[n];
      #pragma unroll
      for (int w = 0; w < 8; ++w) a += part[(w*4 + c)*32 + r];
      P.hh1[(size_t)r*1024 + n] = 0.5f * a * (1.0f + erff(a / 1.41421356237309504880f));
    }
    gbarAll(P.bar, ++epoch, done);

    // ---- S9: head2, N=1024, K=1024, 4 cols/block, gelu ----
    mm_part<4,1024,1024>(P.o2w, P.hh1, bid*4, part);
    if (tid < 128){
      int r = tid & 31, c = tid >> 5;
      int n = bid*4 + c;
      float a = P.o2b[n];
      #pragma unroll
      for (int w = 0; w < 8; ++w) a += part[(w*4 + c)*32 + r];
      P.hh2[(size_t)r*1024 + n] = 0.5f * a * (1.0f + erff(a / 1.41421356237309504880f));
    }
    gbarAll(P.bar, ++epoch, done);

    // ---- S10: sample (32 row blocks) + embed for next step ----
    if (bid < 32){
      int rb = bid, v = tid;
      float* hrow = smem;                 // 1024
      float* sred = smem + 1024;          // 8
      int*   sidx = (int*)(smem + 1032);  // 2
      for (int k = tid; k < 1024; k += NTHR) hrow[k] = P.hh2[(size_t)rb*1024 + k];
      __syncthreads();
      float sv = 0.f;
      if (tid < 128){
        float acc = P.o3b[v] + dot_f4(hrow, P.o3w + (size_t)v*1024, 1024);
        sv = acc / 0.1f;
      }
      float mx = (tid < 128) ? sv : -INFINITY;
      #pragma unroll
      for (int off = 32; off; off >>= 1) mx = fmaxf(mx, __shfl_xor(mx, off));
      __syncthreads();
      if (tid < 128 && (tid & 63) == 0) sred[tid >> 6] = mx;
      __syncthreads();
      mx = fmaxf(sred[0], sred[1]);
      float e = (tid < 128) ? expf(sv - mx) : 0.f;
      float sum = e;
      #pragma unroll
      for (int off = 32; off; off >>= 1) sum += __shfl_xor(sum, off);
      __syncthreads();
      if (tid < 128 && (tid & 63) == 0) sred[tid >> 6] = sum;
      __syncthreads();
      sum = sred[0] + sred[1];
      float bv = -INFINITY; int bi = 0x7fffffff;
      if (tid < 128){
        float lp = (sv - mx) - logf(sum);
        uint32_t kk0, kk1, o0, o1;
        tf2x32(0u, 1u, 0u, (uint32_t)t, &kk0, &kk1);
        tf2x32(kk0, kk1, 0u, (uint32_t)(rb*VV + v), &o0, &o1);
        uint32_t bits = o0 ^ o1;
        float u = __uint_as_float((bits >> 9) | 0x3F800000u) - 1.0f;
        float gg = -logf(-logf(u + 1e-9f) + 1e-9f);
        bv = lp + gg; bi = v;
      }
      #pragma unroll
      for (int off = 32; off; off >>= 1){
        float ov = __shfl_xor(bv, off);
        int   oi = __shfl_xor(bi, off);
        if (ov > bv || (ov == bv && oi < bi)){ bv = ov; bi = oi; }
      }
      __syncthreads();
      if (tid < 128 && (tid & 63) == 0){ sred[tid >> 6] = bv; sidx[tid >> 6] = bi; }
      __syncthreads();
      if (tid == 0){
        float v0 = sred[0], v1 = sred[1]; int i0 = sidx[0], i1 = sidx[1];
        int tok = (v1 > v0 || (v1 == v0 && i1 < i0)) ? i1 : i0;
        P.pred[rb*TT + t] = tok;
        *stok = tok;
      }
      __syncthreads();
      // embed position t for next step (p = t)
      {
        int tok = *stok, d = tid;
        int i = d >> 1;
        float c = P.cosb[t*256 + i], s = P.sinb[t*256 + i];
        float e0 = P.emb[(size_t)tok*DD + (d & ~1)];
        float e1 = P.emb[(size_t)tok*DD + (d | 1)];
        P.xl[rb*DD + d] = (d & 1) ? fmaf(e1, c, e0*s) : fmaf(e0, c, -(e1*s));
      }
    }
    gbarAll(P.bar, ++epoch, done);
  }
}

// ---------------- host ----------------
extern "C" void kernel_launch(void* const* d_in, const int* in_sizes, int n_in,
                              void* d_out, int out_size, void* d_ws, size_t ws_size,
                              hipStream_t stream){
  (void)in_sizes; (void)n_in; (void)out_size; (void)ws_size;
  const float* mol      = (const float*)d_in[1];
  const float* ca_in_w  = (const float*)d_in[7];
  const float* ca_in_b  = (const float*)d_in[8];
  const float* ca_out_w = (const float*)d_in[9];
  const float* ca_out_b = (const float*)d_in[10];

  KParams P;
  P.emb = (const float*)d_in[2];
  P.saw = (const float*)d_in[3];
  P.sab = (const float*)d_in[4];
  P.sow = (const float*)d_in[5];
  P.sob = (const float*)d_in[6];
  P.f1w = (const float*)d_in[11];
  P.f1b = (const float*)d_in[12];
  P.f2w = (const float*)d_in[13];
  P.f2b = (const float*)d_in[14];
  P.g1  = (const float*)d_in[15];
  P.b1  = (const float*)d_in[16];
  P.g2  = (const float*)d_in[17];
  P.b2  = (const float*)d_in[18];
  P.g3  = (const float*)d_in[19];
  P.b3  = (const float*)d_in[20];
  P.fg  = (const float*)d_in[21];
  P.fb  = (const float*)d_in[22];
  P.o1w = (const float*)d_in[23];
  P.o1b = (const float*)d_in[24];
  P.o2w = (const float*)d_in[25];
  P.o2b = (const float*)d_in[26];
  P.o3w = (const float*)d_in[27];
  P.o3b = (const float*)d_in[28];

  unsigned* bar = (unsigned*)d_ws;          // 2048 uints
  float* ws = (float*)d_ws + 2048;
  float* cosb   = ws;                       // 16384
  float* sinb   = cosb + 16384;             // 16384
  float* ca_tmp = sinb + 16384;             // 65536
  float* cac    = ca_tmp + 65536;           // 65536
  float* kc     = cac + 65536;              // 4194304
  float* vc     = kc + 4194304;             // 4194304
  float* xl     = vc + 4194304;             // 16384
  float* qb     = xl + 16384;               // 16384
  float* at     = qb + 16384;               // 16384
  float* ao     = at + 16384;               // 16384
  float* x2     = ao + 16384;               // 16384
  float* fo     = x2 + 16384;               // 16384
  float* h1     = fo + 16384;               // 65536
  float* xf     = h1 + 65536;               // 16384
  float* hh1    = xf + 16384;               // 32768
  float* hh2    = hh1 + 32768;              // 32768

  P.cosb = cosb; P.sinb = sinb; P.cac = cac;
  P.kc = kc; P.vc = vc; P.xl = xl; P.qb = qb; P.at = at; P.ao = ao;
  P.x2 = x2; P.fo = fo; P.h1 = h1; P.xf = xf; P.hh1 = hh1; P.hh2 = hh2;
  P.pred = (int*)d_out;
  P.bar = bar;

  k_binit<<<1, 1024, 0, stream>>>(bar, P.pred);
  k_tables<<<64, 256, 0, stream>>>(cosb, sinb);
  k_ca1<<<256, 256, 0, stream>>>(mol, ca_in_w, ca_in_b, ca_tmp);
  k_ca2<<<256, 256, 0, stream>>>(ca_tmp, ca_out_w, ca_out_b, cac);

  k_persist<<<NBLK, NTHR, 0, stream>>>(P);
}

// Round 8
// 32965.521 us; speedup vs baseline: 1.0923x; 1.0923x over previous
//
#include <hip/hip_runtime.h>
#include <stdint.h>
#include <stddef.h>

#define BB 32
#define TT 64
#define DD 512
#define HH 8
#define HDIM 64
#define LL 4
#define FFD 2048
#define VV 128

#define NBLK 256
#define NTHR 512

// ---------------- threefry2x32 (20 rounds), matches JAX ----------------
__host__ __device__ inline uint32_t rotl32(uint32_t v, int n){ return (v << n) | (v >> (32 - n)); }

__host__ __device__ inline void tf2x32(uint32_t k0, uint32_t k1, uint32_t x0, uint32_t x1,
                                       uint32_t* o0, uint32_t* o1){
  uint32_t ks2 = k0 ^ k1 ^ 0x1BD11BDAu;
  x0 += k0; x1 += k1;
  x0 += x1; x1 = rotl32(x1,13); x1 ^= x0;
  x0 += x1; x1 = rotl32(x1,15); x1 ^= x0;
  x0 += x1; x1 = rotl32(x1,26); x1 ^= x0;
  x0 += x1; x1 = rotl32(x1, 6); x1 ^= x0;
  x0 += k1; x1 += ks2 + 1u;
  x0 += x1; x1 = rotl32(x1,17); x1 ^= x0;
  x0 += x1; x1 = rotl32(x1,29); x1 ^= x0;
  x0 += x1; x1 = rotl32(x1,16); x1 ^= x0;
  x0 += x1; x1 = rotl32(x1,24); x1 ^= x0;
  x0 += ks2; x1 += k0 + 2u;
  x0 += x1; x1 = rotl32(x1,13); x1 ^= x0;
  x0 += x1; x1 = rotl32(x1,15); x1 ^= x0;
  x0 += x1; x1 = rotl32(x1,26); x1 ^= x0;
  x0 += x1; x1 = rotl32(x1, 6); x1 ^= x0;
  x0 += k0; x1 += k1 + 3u;
  x0 += x1; x1 = rotl32(x1,17); x1 ^= x0;
  x0 += x1; x1 = rotl32(x1,29); x1 ^= x0;
  x0 += x1; x1 = rotl32(x1,16); x1 ^= x0;
  x0 += x1; x1 = rotl32(x1,24); x1 ^= x0;
  x0 += k1; x1 += ks2 + 4u;
  x0 += x1; x1 = rotl32(x1,13); x1 ^= x0;
  x0 += x1; x1 = rotl32(x1,15); x1 ^= x0;
  x0 += x1; x1 = rotl32(x1,26); x1 ^= x0;
  x0 += x1; x1 = rotl32(x1, 6); x1 ^= x0;
  x0 += ks2; x1 += k0 + 5u;
  *o0 = x0; *o1 = x1;
}

// ---------------- coherent (device-scope, uncached) accessors ----------------
__device__ __forceinline__ float cload(const float* p){
  return __hip_atomic_load(p, __ATOMIC_RELAXED, __HIP_MEMORY_SCOPE_AGENT);
}
__device__ __forceinline__ void cstore(float* p, float v){
  __hip_atomic_store(p, v, __ATOMIC_RELAXED, __HIP_MEMORY_SCOPE_AGENT);
}
__device__ __forceinline__ int cloadi(const int* p){
  return __hip_atomic_load(p, __ATOMIC_RELAXED, __HIP_MEMORY_SCOPE_AGENT);
}
__device__ __forceinline__ void cstorei(int* p, int v){
  __hip_atomic_store(p, v, __ATOMIC_RELAXED, __HIP_MEMORY_SCOPE_AGENT);
}

// ---------------- helpers ----------------
__device__ inline float dot_f4(const float* __restrict__ a, const float* __restrict__ w, int K){
  float acc = 0.f;
  const float4* a4 = (const float4*)a;
  const float4* w4 = (const float4*)w;
  int K4 = K >> 2;
  for (int k = 0; k < K4; ++k){
    float4 av = a4[k], wv = w4[k];
    acc = fmaf(av.x, wv.x, acc);
    acc = fmaf(av.y, wv.y, acc);
    acc = fmaf(av.z, wv.z, acc);
    acc = fmaf(av.w, wv.w, acc);
  }
  return acc;
}

// LayerNorm across a 512-thread block (one value per thread). Round-1 exact order.
__device__ inline float block_ln(float v, float g, float bb, float* red){
  __syncthreads();
  float s = v;
  #pragma unroll
  for (int off = 32; off; off >>= 1) s += __shfl_xor(s, off);
  if ((threadIdx.x & 63) == 0) red[threadIdx.x >> 6] = s;
  __syncthreads();
  float mu = (red[0]+red[1]+red[2]+red[3]+red[4]+red[5]+red[6]+red[7]) * (1.0f/512.0f);
  float dv = v - mu;
  float sq = dv * dv;
  #pragma unroll
  for (int off = 32; off; off >>= 1) sq += __shfl_xor(sq, off);
  __syncthreads();
  if ((threadIdx.x & 63) == 0) red[threadIdx.x >> 6] = sq;
  __syncthreads();
  float var = (red[0]+red[1]+red[2]+red[3]+red[4]+red[5]+red[6]+red[7]) * (1.0f/512.0f);
  return dv * (1.0f / sqrtf(var + 1e-5f)) * g + bb;
}

// ---------------- global barrier v4: FENCE-FREE (all shared data uses coherent ops) ----
// bar: sub[i]=bar[i*16] (i<32), mid[j]=bar[512+j*16] (j<4), root=bar[640], flag[i]=bar[1024+i*16]
__device__ __forceinline__ void gbarAll(unsigned* bar, unsigned epoch, int* done){
  const int tid = threadIdx.x;
  const int sub = blockIdx.x >> 3;
  __syncthreads();   // compiler drains vmcnt/lgkmcnt -> coherent stores at coherence point
  if (tid == 0){
    int c = 0;
    if (__hip_atomic_fetch_add(bar + sub*16, 1u, __ATOMIC_RELAXED, __HIP_MEMORY_SCOPE_AGENT) == 7u){
      int mid = sub >> 3;
      if (__hip_atomic_fetch_add(bar + 512 + mid*16, 1u, __ATOMIC_RELAXED, __HIP_MEMORY_SCOPE_AGENT) == 7u){
        if (__hip_atomic_fetch_add(bar + 640, 1u, __ATOMIC_RELAXED, __HIP_MEMORY_SCOPE_AGENT) == 3u)
          c = 1;
      }
    }
    *done = c;
  }
  __syncthreads();
  if (*done){
    if (tid < 32)      __hip_atomic_store(bar + tid*16,            0u, __ATOMIC_RELAXED, __HIP_MEMORY_SCOPE_AGENT);
    else if (tid < 36) __hip_atomic_store(bar + 512 + (tid-32)*16, 0u, __ATOMIC_RELAXED, __HIP_MEMORY_SCOPE_AGENT);
    else if (tid == 36)__hip_atomic_store(bar + 640,               0u, __ATOMIC_RELAXED, __HIP_MEMORY_SCOPE_AGENT);
    __syncthreads();   // resets drained before flags published
    if (tid < 32) __hip_atomic_store(bar + 1024 + tid*16, epoch, __ATOMIC_RELAXED, __HIP_MEMORY_SCOPE_AGENT);
  } else {
    if (tid == 0){
      while (__hip_atomic_load(bar + 1024 + sub*16, __ATOMIC_RELAXED, __HIP_MEMORY_SCOPE_AGENT) < epoch)
        __builtin_amdgcn_s_sleep(1);
    }
  }
  __syncthreads();
}

// ---------------- setup kernels ----------------
__global__ void k_tables(float* __restrict__ cosb, float* __restrict__ sinb){
  int tid = blockIdx.x * blockDim.x + threadIdx.x;  // TT*256
  int p = tid >> 8, i = tid & 255;
  float sv = (2.0f * (float)i + 204.8f) / 716.8f;
  float scale = powf(sv, (float)p / 16.0f);
  float invf = 1.0f / powf(10000.0f, (float)i / 256.0f);
  float ang = (float)p * invf;
  cosb[tid] = cosf(ang) * scale;
  sinb[tid] = sinf(ang) * scale;
}

__global__ void k_ca1(const float* __restrict__ mol, const float* __restrict__ w,
                      const float* __restrict__ bias, float* __restrict__ tmp){
  int tid = blockIdx.x * blockDim.x + threadIdx.x;  // LL*BB*DD
  int l = tid >> 14; int r = tid & 16383; int b = r >> 9; int d = r & 511;
  const float* wr = w + (size_t)l*3*DD*DD + (size_t)(2*DD + d)*DD;
  tmp[tid] = bias[l*3*DD + 2*DD + d] + dot_f4(mol + (size_t)b*DD, wr, DD);
}

__global__ void k_ca2(const float* __restrict__ tmp, const float* __restrict__ w,
                      const float* __restrict__ bias, float* __restrict__ cac){
  int tid = blockIdx.x * blockDim.x + threadIdx.x;  // LL*BB*DD
  int l = tid >> 14; int r = tid & 16383; int b = r >> 9; int d = r & 511;
  const float* wr = w + (size_t)l*DD*DD + (size_t)d*DD;
  cac[tid] = bias[l*DD + d] + dot_f4(tmp + ((size_t)l*BB + b)*DD, wr, DD);
}

__global__ void k_binit(unsigned* __restrict__ bar, int* __restrict__ pred){
  int tid = threadIdx.x;            // 1024 threads
  bar[tid] = 0u;
  bar[tid + 1024] = 0u;
  pred[tid]        = ((tid & (TT-1)) == 0) ? 1 : 0;
  pred[tid + 1024] = (((tid + 1024) & (TT-1)) == 0) ? 1 : 0;
}

// ---------------- LDS-staged matmul partials ----------------
// W [N][KTOT] row-major cached; sact = LDS slice [32][512] (pitch 516) of act k-range [kb*512, kb*512+512).
// Same task decomposition and per-chunk k-ascending fmaf chains as r7's mm_part.
#define APITCH 516

template<int C, int KTOT>
__device__ __forceinline__ void mm_lds(const float* __restrict__ W, const float* __restrict__ sact,
                                       int kb, int n0, float* __restrict__ part){
  const int tid = threadIdx.x;
  const int KC = KTOT/8;
  #pragma unroll
  for (int i = 0; i < (C*256)/512; ++i){
    int tau = tid + i*512;
    int r = tau & 31, rest = tau >> 5;
    int c = rest % C, w = rest / C;
    if ((KTOT > 512) && (((w*KC) >> 9) != kb)) continue;   // chunk not in this LDS slice
    const float4* wr = (const float4*)(W + (size_t)(n0 + c)*KTOT + w*KC);
    const float4* ar = (const float4*)(sact + (size_t)r*APITCH + (w*KC - kb*512));
    float acc = 0.f;
    #pragma unroll 16
    for (int k4 = 0; k4 < KC/4; ++k4){
      float4 wv = wr[k4], av = ar[k4];
      acc = fmaf(av.x, wv.x, acc);
      acc = fmaf(av.y, wv.y, acc);
      acc = fmaf(av.z, wv.z, acc);
      acc = fmaf(av.w, wv.w, acc);
    }
    part[(w*C + c)*32 + r] = acc;
  }
}

// ---------------- persistent decode kernel ----------------
struct KParams {
  const float *emb, *saw, *sab, *sow, *sob, *f1w, *f1b, *f2w, *f2b;
  const float *g1,*b1,*g2,*b2,*g3,*b3,*fg,*fb;
  const float *o1w,*o1b,*o2w,*o2b,*o3w,*o3b;
  const float *cosb,*sinb,*cac;
  float *kc,*vc,*xl,*qb,*at,*ao,*x2,*fo,*h1,*xf,*hh1,*hh2;
  int *pred;
  unsigned *bar;
};

__global__ __launch_bounds__(NTHR) void k_persist(KParams P){
  const int bid = blockIdx.x, tid = threadIdx.x;
  const int lane = tid & 63;
  __shared__ __align__(16) float smem[2176];
  __shared__ __align__(16) float sact[32*APITCH];   // 66 KB activation slice
  float* part = smem;                  // 2048
  float* red  = smem + 2048;           // 8
  int*   redi = (int*)(smem + 2056);   // 2
  int*   stok = (int*)(smem + 2060);   // 1
  int*   done = (int*)(smem + 2064);   // 1
  unsigned epoch = 0;

  // stage helper: load act[32][512] slice (k offset kb*512) into sact, coherent scalar loads
  #define STAGE_ACT(ACT, ASTRIDE, KB)                                            \
    for (int i_ = tid; i_ < 32*512; i_ += NTHR){                                 \
      int r_ = i_ >> 9, k_ = i_ & 511;                                           \
      sact[r_*APITCH + k_] = cload((ACT) + (size_t)r_*(ASTRIDE) + (KB)*512 + k_);\
    }

  // ---- pre-loop: embed position 0 (rows on blocks 0..31) ----
  if (bid < 32){
    int rb = bid, d = tid;
    int tok = cloadi(P.pred + rb*TT + 0);
    int i = d >> 1;
    float c = P.cosb[0*256 + i], s = P.sinb[0*256 + i];
    float e0 = P.emb[(size_t)tok*DD + (d & ~1)];
    float e1 = P.emb[(size_t)tok*DD + (d | 1)];
    cstore(P.xl + rb*DD + d, (d & 1) ? fmaf(e1, c, e0*s) : fmaf(e0, c, -(e1*s)));
  }
  gbarAll(P.bar, ++epoch, done);

  for (int t = 1; t < TT; ++t){
    const int pp = t - 1;

    for (int l = 0; l < LL; ++l){
      // ---- S1: QKV, N=1536, 6 cols/block ----
      STAGE_ACT(P.xl, 512, 0);
      __syncthreads();
      mm_lds<6,512>(P.saw + (size_t)l*1536*512, sact, 0, bid*6, part);
      __syncthreads();
      if (tid < 192){
        int r = tid & 31, c = tid >> 5;
        int n = bid*6 + c;
        float s = P.sab[l*1536 + n];
        #pragma unroll
        for (int w = 0; w < 8; ++w) s += part[(w*6 + c)*32 + r];
        if (n < DD){
          cstore(P.qb + (size_t)r*DD + n, s);
        } else if (n < 2*DD){
          int h = (n - DD) >> 6, hd = (n - DD) & 63;
          cstore(P.kc + ((((size_t)l*BB + r)*HH + h)*TT + pp)*HDIM + hd, s);
        } else {
          int h = (n - 2*DD) >> 6, hd = (n - 2*DD) & 63;
          cstore(P.vc + ((((size_t)l*BB + r)*HH + h)*TT + pp)*HDIM + hd, s);
        }
      }
      gbarAll(P.bar, ++epoch, done);

      // ---- S2: attention, block = (row, head), 1 wave ----
      {
        int rb = bid >> 3, h = bid & 7;
        float* qs = smem; float* ps = smem + 64;
        if (tid < 64) qs[tid] = cload(P.qb + (size_t)rb*DD + h*HDIM + tid);
        __syncthreads();
        if (tid < 64){
          const float* kb = P.kc + (((size_t)l*BB + rb)*HH + h)*TT*HDIM;
          float s = -INFINITY;
          if (lane <= pp && cloadi(P.pred + rb*TT + lane) != 0){
            const float* kr = kb + lane*HDIM;
            float acc = 0.f;
            #pragma unroll
            for (int k2 = 0; k2 < HDIM; ++k2) acc = fmaf(qs[k2], cload(kr + k2), acc);
            s = acc * 0.125f;
          }
          float mx = s;
          #pragma unroll
          for (int off = 32; off; off >>= 1) mx = fmaxf(mx, __shfl_xor(mx, off));
          float e = (s == -INFINITY) ? 0.f : expf(s - mx);
          float sum = e;
          #pragma unroll
          for (int off = 32; off; off >>= 1) sum += __shfl_xor(sum, off);
          ps[lane] = e / sum;
          const float* vb = P.vc + (((size_t)l*BB + rb)*HH + h)*TT*HDIM;
          float o = 0.f;
          int jj = 0;
          for (; jj + 8 <= t; jj += 8){
            float vv[8];
            #pragma unroll
            for (int u = 0; u < 8; ++u) vv[u] = cload(vb + (jj+u)*HDIM + lane);
            #pragma unroll
            for (int u = 0; u < 8; ++u) o = fmaf(ps[jj+u], vv[u], o);
          }
          for (; jj <= pp; ++jj) o = fmaf(ps[jj], cload(vb + jj*HDIM + lane), o);
          cstore(P.at + (size_t)rb*DD + h*HDIM + lane, o);
        }
      }
      gbarAll(P.bar, ++epoch, done);

      // ---- S3: oproj, N=512, 2 cols/block ----
      STAGE_ACT(P.at, 512, 0);
      __syncthreads();
      mm_lds<2,512>(P.sow + (size_t)l*512*512, sact, 0, bid*2, part);
      __syncthreads();
      if (tid < 64){
        int r = tid & 31, c = tid >> 5;
        int n = bid*2 + c;
        float s = P.sob[l*DD + n];
        #pragma unroll
        for (int w = 0; w < 8; ++w) s += part[(w*2 + c)*32 + r];
        cstore(P.ao + (size_t)r*DD + n, s);
      }
      gbarAll(P.bar, ++epoch, done);

      // ---- S4: residual + ln1 + cross const + ln2 (32 row blocks) ----
      if (bid < 32){
        int b = bid, d = tid;
        float xv = cload(P.xl + (size_t)b*DD + d) + cload(P.ao + (size_t)b*DD + d);
        xv = block_ln(xv, P.g1[l*DD + d], P.b1[l*DD + d], red);
        xv = xv + P.cac[((size_t)l*BB + b)*DD + d];
        xv = block_ln(xv, P.g2[l*DD + d], P.b2[l*DD + d], red);
        cstore(P.x2 + (size_t)b*DD + d, xv);
      }
      gbarAll(P.bar, ++epoch, done);

      // ---- S5: FF1, N=2048, 8 cols/block, silu ----
      STAGE_ACT(P.x2, 512, 0);
      __syncthreads();
      mm_lds<8,512>(P.f1w + (size_t)l*2048*512, sact, 0, bid*8, part);
      __syncthreads();
      if (tid < 256){
        int r = tid & 31, c = tid >> 5;
        int n = bid*8 + c;
        float v = P.f1b[l*FFD + n];
        #pragma unroll
        for (int w = 0; w < 8; ++w) v += part[(w*8 + c)*32 + r];
        cstore(P.h1 + (size_t)r*FFD + n, v / (1.0f + expf(-v)));
      }
      gbarAll(P.bar, ++epoch, done);

      // ---- S6: FF2, N=512, K=2048 (4 LDS phases), 2 cols/block ----
      for (int kb = 0; kb < 4; ++kb){
        STAGE_ACT(P.h1, 2048, kb);
        __syncthreads();
        mm_lds<2,2048>(P.f2w + (size_t)l*512*2048, sact, kb, bid*2, part);
        __syncthreads();
      }
      if (tid < 64){
        int r = tid & 31, c = tid >> 5;
        int n = bid*2 + c;
        float s = P.f2b[l*DD + n];
        #pragma unroll
        for (int w = 0; w < 8; ++w) s += part[(w*2 + c)*32 + r];
        cstore(P.fo + (size_t)r*DD + n, s);
      }
      gbarAll(P.bar, ++epoch, done);

      // ---- S7: residual + ln3 (+ final ln at last layer) (32 row blocks) ----
      if (bid < 32){
        int b = bid, d = tid;
        float y = cload(P.x2 + (size_t)b*DD + d) + cload(P.fo + (size_t)b*DD + d);
        float xv = block_ln(y, P.g3[l*DD + d], P.b3[l*DD + d], red);
        if (l < LL-1){
          cstore(P.xl + (size_t)b*DD + d, xv);
        } else {
          float o = block_ln(xv, P.fg[d], P.fb[d], red);
          cstore(P.xf + (size_t)b*DD + d, o);
        }
      }
      gbarAll(P.bar, ++epoch, done);
    }

    // ---- S8: head1, N=1024, 4 cols/block, gelu ----
    STAGE_ACT(P.xf, 512, 0);
    __syncthreads();
    mm_lds<4,512>(P.o1w, sact, 0, bid*4, part);
    __syncthreads();
    if (tid < 128){
      int r = tid & 31, c = tid >> 5;
      int n = bid*4 + c;
      float a = P.o1b[n];
      #pragma unroll
      for (int w = 0; w < 8; ++w) a += part[(w*4 + c)*32 + r];
      cstore(P.hh1 + (size_t)r*1024 + n, 0.5f * a * (1.0f + erff(a / 1.41421356237309504880f)));
    }
    gbarAll(P.bar, ++epoch, done);

    // ---- S9: head2, N=1024, K=1024 (2 LDS phases), 4 cols/block, gelu ----
    for (int kb = 0; kb < 2; ++kb){
      STAGE_ACT(P.hh1, 1024, kb);
      __syncthreads();
      mm_lds<4,1024>(P.o2w, sact, kb, bid*4, part);
      __syncthreads();
    }
    if (tid < 128){
      int r = tid & 31, c = tid >> 5;
      int n = bid*4 + c;
      float a = P.o2b[n];
      #pragma unroll
      for (int w = 0; w < 8; ++w) a += part[(w*4 + c)*32 + r];
      cstore(P.hh2 + (size_t)r*1024 + n, 0.5f * a * (1.0f + erff(a / 1.41421356237309504880f)));
    }
    gbarAll(P.bar, ++epoch, done);

    // ---- S10: sample (32 row blocks) + embed for next step ----
    if (bid < 32){
      int rb = bid, v = tid;
      float* hrow = smem;                 // 1024
      float* sred = smem + 1024;          // 8
      int*   sidx = (int*)(smem + 1032);  // 2
      for (int k = tid; k < 1024; k += NTHR) hrow[k] = cload(P.hh2 + (size_t)rb*1024 + k);
      __syncthreads();
      float sv = 0.f;
      if (tid < 128){
        float acc = P.o3b[v] + dot_f4(hrow, P.o3w + (size_t)v*1024, 1024);
        sv = acc / 0.1f;
      }
      float mx = (tid < 128) ? sv : -INFINITY;
      #pragma unroll
      for (int off = 32; off; off >>= 1) mx = fmaxf(mx, __shfl_xor(mx, off));
      __syncthreads();
      if (tid < 128 && (tid & 63) == 0) sred[tid >> 6] = mx;
      __syncthreads();
      mx = fmaxf(sred[0], sred[1]);
      float e = (tid < 128) ? expf(sv - mx) : 0.f;
      float sum = e;
      #pragma unroll
      for (int off = 32; off; off >>= 1) sum += __shfl_xor(sum, off);
      __syncthreads();
      if (tid < 128 && (tid & 63) == 0) sred[tid >> 6] = sum;
      __syncthreads();
      sum = sred[0] + sred[1];
      float bv = -INFINITY; int bi = 0x7fffffff;
      if (tid < 128){
        float lp = (sv - mx) - logf(sum);
        uint32_t kk0, kk1, o0, o1;
        tf2x32(0u, 1u, 0u, (uint32_t)t, &kk0, &kk1);
        tf2x32(kk0, kk1, 0u, (uint32_t)(rb*VV + v), &o0, &o1);
        uint32_t bits = o0 ^ o1;
        float u = __uint_as_float((bits >> 9) | 0x3F800000u) - 1.0f;
        float gg = -logf(-logf(u + 1e-9f) + 1e-9f);
        bv = lp + gg; bi = v;
      }
      #pragma unroll
      for (int off = 32; off; off >>= 1){
        float ov = __shfl_xor(bv, off);
        int   oi = __shfl_xor(bi, off);
        if (ov > bv || (ov == bv && oi < bi)){ bv = ov; bi = oi; }
      }
      __syncthreads();
      if (tid < 128 && (tid & 63) == 0){ sred[tid >> 6] = bv; sidx[tid >> 6] = bi; }
      __syncthreads();
      if (tid == 0){
        float v0 = sred[0], v1 = sred[1]; int i0 = sidx[0], i1 = sidx[1];
        int tok = (v1 > v0 || (v1 == v0 && i1 < i0)) ? i1 : i0;
        cstorei(P.pred + rb*TT + t, tok);
        *stok = tok;
      }
      __syncthreads();
      // embed position t for next step
      {
        int tok = *stok, d = tid;
        int i = d >> 1;
        float c = P.cosb[t*256 + i], s = P.sinb[t*256 + i];
        float e0 = P.emb[(size_t)tok*DD + (d & ~1)];
        float e1 = P.emb[(size_t)tok*DD + (d | 1)];
        cstore(P.xl + rb*DD + d, (d & 1) ? fmaf(e1, c, e0*s) : fmaf(e0, c, -(e1*s)));
      }
    }
    gbarAll(P.bar, ++epoch, done);
  }
  #undef STAGE_ACT
}

// ---------------- host ----------------
extern "C" void kernel_launch(void* const* d_in, const int* in_sizes, int n_in,
                              void* d_out, int out_size, void* d_ws, size_t ws_size,
                              hipStream_t stream){
  (void)in_sizes; (void)n_in; (void)out_size; (void)ws_size;
  const float* mol      = (const float*)d_in[1];
  const float* ca_in_w  = (const float*)d_in[7];
  const float* ca_in_b  = (const float*)d_in[8];
  const float* ca_out_w = (const float*)d_in[9];
  const float* ca_out_b = (const float*)d_in[10];

  KParams P;
  P.emb = (const float*)d_in[2];
  P.saw = (const float*)d_in[3];
  P.sab = (const float*)d_in[4];
  P.sow = (const float*)d_in[5];
  P.sob = (const float*)d_in[6];
  P.f1w = (const float*)d_in[11];
  P.f1b = (const float*)d_in[12];
  P.f2w = (const float*)d_in[13];
  P.f2b = (const float*)d_in[14];
  P.g1  = (const float*)d_in[15];
  P.b1  = (const float*)d_in[16];
  P.g2  = (const float*)d_in[17];
  P.b2  = (const float*)d_in[18];
  P.g3  = (const float*)d_in[19];
  P.b3  = (const float*)d_in[20];
  P.fg  = (const float*)d_in[21];
  P.fb  = (const float*)d_in[22];
  P.o1w = (const float*)d_in[23];
  P.o1b = (const float*)d_in[24];
  P.o2w = (const float*)d_in[25];
  P.o2b = (const float*)d_in[26];
  P.o3w = (const float*)d_in[27];
  P.o3b = (const float*)d_in[28];

  unsigned* bar = (unsigned*)d_ws;          // 2048 uints
  float* ws = (float*)d_ws + 2048;
  float* cosb   = ws;                       // 16384
  float* sinb   = cosb + 16384;             // 16384
  float* ca_tmp = sinb + 16384;             // 65536
  float* cac    = ca_tmp + 65536;           // 65536
  float* kc     = cac + 65536;              // 4194304
  float* vc     = kc + 4194304;             // 4194304
  float* xl     = vc + 4194304;             // 16384
  float* qb     = xl + 16384;               // 16384
  float* at     = qb + 16384;               // 16384
  float* ao     = at + 16384;               // 16384
  float* x2     = ao + 16384;               // 16384
  float* fo     = x2 + 16384;               // 16384
  float* h1     = fo + 16384;               // 65536
  float* xf     = h1 + 65536;               // 16384
  float* hh1    = xf + 16384;               // 32768
  float* hh2    = hh1 + 32768;              // 32768

  P.cosb = cosb; P.sinb = sinb; P.cac = cac;
  P.kc = kc; P.vc = vc; P.xl = xl; P.qb = qb; P.at = at; P.ao = ao;
  P.x2 = x2; P.fo = fo; P.h1 = h1; P.xf = xf; P.hh1 = hh1; P.hh2 = hh2;
  P.pred = (int*)d_out;
  P.bar = bar;

  k_binit<<<1, 1024, 0, stream>>>(bar, P.pred);
  k_tables<<<64, 256, 0, stream>>>(cosb, sinb);
  k_ca1<<<256, 256, 0, stream>>>(mol, ca_in_w, ca_in_b, ca_tmp);
  k_ca2<<<256, 256, 0, stream>>>(ca_tmp, ca_out_w, ca_out_b, cac);

  k_persist<<<NBLK, NTHR, 0, stream>>>(P);
}